// Round 9
// baseline (752.725 us; speedup 1.0000x reference)
//
#include <hip/hip_runtime.h>
#include <cstdint>
#include <cstddef>

#define NNODES 50000
#define NPAD   50048        // 391*128, padded M for P/Q GEMM
#define NRELS  256
#define DIM    256
#define TT     24
#define EE     20000
#define BATCH  16
#define SEQQ   7

typedef __bf16 bf16;
typedef __bf16 bf16x4 __attribute__((ext_vector_type(4)));
typedef __bf16 bf16x8 __attribute__((ext_vector_type(8)));
typedef float  f32x4  __attribute__((ext_vector_type(4)));

// async global->LDS, 16B per lane; dest is wave-uniform base (+lane*16 by HW)
__device__ __forceinline__ void gload16(const void* g, void* l){
  __builtin_amdgcn_global_load_lds((const __attribute__((address_space(1))) void*)g,
                                   (__attribute__((address_space(3))) void*)l, 16, 0, 0);
}

// ---------------- prep kernels ----------------

__global__ void k_cvt8(const float* __restrict__ in, bf16* __restrict__ out, int n8){
  int i = blockIdx.x*256 + threadIdx.x;
  if (i >= n8) return;
  const float4* p = (const float4*)in + (size_t)i*2;
  float4 a = p[0], b = p[1];
  bf16x8 o;
  o[0]=(bf16)a.x; o[1]=(bf16)a.y; o[2]=(bf16)a.z; o[3]=(bf16)a.w;
  o[4]=(bf16)b.x; o[5]=(bf16)b.y; o[6]=(bf16)b.z; o[7]=(bf16)b.w;
  ((bf16x8*)out)[i] = o;
}

// Fused edge weight, transposed: WbT[n][k], k in [0,768) = [W1 | W2fold | W3].
__global__ void k_build_wbt(const float* __restrict__ tW, const float* __restrict__ eW,
                            bf16* __restrict__ WbT){
  int n = blockIdx.x, j = threadIdx.x;
  WbT[(size_t)n*768 + j]       = (bf16)eW[(size_t)j*256 + n];
  WbT[(size_t)n*768 + 512 + j] = (bf16)eW[(size_t)(512+j)*256 + n];
  float acc = 0.f;
  for (int m=0; m<256; ++m) acc += tW[(size_t)j*256 + m] * eW[(size_t)(256+m)*256 + n];
  WbT[(size_t)n*768 + 256 + j] = (bf16)acc;
}

// fused bias: bfused[n] = edge_w_b[n] + sum_m text_w_b[m]*W2[m][n]
__global__ void k_bias(const float* __restrict__ tb, const float* __restrict__ eW,
                       const float* __restrict__ eb, float* __restrict__ bf){
  int n = threadIdx.x;
  float acc = eb[n];
  for (int m=0; m<256; ++m) acc += tb[m] * eW[(size_t)(256+m)*256 + n];
  bf[n] = acc;
}

// gru weight [256][768] -> transposed bf16 [768][256]
__global__ void k_gruWT(const float* __restrict__ W, bf16* __restrict__ WT){
  int n = blockIdx.x, k = threadIdx.x;
  WT[(size_t)n*256 + k] = (bf16)W[(size_t)k*768 + n];
}

// per-t histogram of rels + exclusive scan
__global__ void k_hist(const int* __restrict__ rel, int* __restrict__ counts,
                       int* __restrict__ offs, int* __restrict__ cursor){
  __shared__ int hist[256];
  __shared__ int scan[256];
  int t = blockIdx.x, tid = threadIdx.x;
  hist[tid] = 0;
  __syncthreads();
  for (int e = tid; e < EE; e += 256) atomicAdd(&hist[rel[(size_t)t*EE + e]], 1);
  __syncthreads();
  int v = hist[tid];
  scan[tid] = v;
  __syncthreads();
  for (int d=1; d<256; d<<=1){
    int add = (tid >= d) ? scan[tid-d] : 0;
    __syncthreads();
    scan[tid] += add;
    __syncthreads();
  }
  int ex = scan[tid] - v;
  counts[t*256+tid] = v;
  offs[t*256+tid]   = ex;
  cursor[t*256+tid] = ex;
}

// bucket edges by (t,rel): emit global text row index and src/dst ids
__global__ void k_perm(const int* __restrict__ rel, const int* __restrict__ esrc,
                       const int* __restrict__ edst, int* __restrict__ cursor,
                       int* __restrict__ gperm, int* __restrict__ src_p,
                       int* __restrict__ dst_p){
  int t = blockIdx.y;
  int e = blockIdx.x*256 + threadIdx.x;
  if (e < EE){
    int r = rel[(size_t)t*EE + e];
    int p = atomicAdd(&cursor[t*256 + r], 1);
    size_t g = (size_t)t*EE + p;
    gperm[g] = t*EE + e;
    src_p[g] = esrc[(size_t)t*EE + e];
    dst_p[g] = edst[(size_t)t*EE + e];
  }
}

// ---------------- node projection GEMM (swapped operands, coalesced stores) ----
__global__ __launch_bounds__(256) void k_projn(
    const bf16* __restrict__ Abf, const bf16* __restrict__ WbT, int koff,
    bf16* __restrict__ out)
{
  int m0 = blockIdx.x*128;
  int tid = threadIdx.x, lane = tid&63, w = tid>>6;
  int l15 = lane&15, lq = lane>>4;
  int c0 = w*64;
  __shared__ __align__(16) bf16 Al[128*32];   // 8KB
  __shared__ __align__(16) bf16 Bl[256*32];   // 16KB

  f32x4 acc[8][4];
  f32x4 z4 = {0.f,0.f,0.f,0.f};
  #pragma unroll
  for (int mi=0;mi<8;++mi)
    #pragma unroll
    for (int ni=0;ni<4;++ni) acc[mi][ni]=z4;

  for (int ks=0; ks<8; ++ks){
    int k0 = ks*32;
    #pragma unroll
    for (int p=0;p<2;++p){
      int c = p*256 + tid;
      int rw = c>>2, prt = c&3;
      int pp = prt ^ ((rw>>1)&3);
      const char* src = (const char*)(Abf + (size_t)(m0+rw)*256 + k0) + pp*16;
      gload16(src, (char*)Al + (size_t)(p*256 + w*64)*16);
    }
    #pragma unroll
    for (int p=0;p<4;++p){
      int c = p*256 + tid;
      int nn = c>>2, prt = c&3;
      int pp = prt ^ ((nn>>1)&3);
      const char* src = (const char*)(WbT + (size_t)nn*768 + koff + k0) + pp*16;
      gload16(src, (char*)Bl + (size_t)(p*256 + w*64)*16);
    }
    __syncthreads();
    bf16x8 b[4];
    #pragma unroll
    for (int ni=0;ni<4;++ni){
      int nn = c0 + ni*16 + l15;
      b[ni] = *(const bf16x8*)((const char*)Bl + (size_t)nn*64 + (size_t)((lq ^ ((nn>>1)&3))*16));
    }
    #pragma unroll
    for (int mi=0;mi<8;++mi){
      int rw = mi*16 + l15;
      bf16x8 a = *(const bf16x8*)((const char*)Al + (size_t)rw*64 + (size_t)((lq ^ ((rw>>1)&3))*16));
      #pragma unroll
      for (int ni=0;ni<4;++ni)
        acc[mi][ni] = __builtin_amdgcn_mfma_f32_16x16x32_bf16(b[ni], a, acc[mi][ni], 0,0,0);
    }
    __syncthreads();
  }
  #pragma unroll
  for (int mi=0;mi<8;++mi){
    int row = m0 + mi*16 + l15;
    #pragma unroll
    for (int ni=0;ni<4;++ni){
      bf16x4 o;
      #pragma unroll
      for (int q=0;q<4;++q) o[q] = (bf16)acc[mi][ni][q];
      *(bf16x4*)(out + (size_t)row*256 + c0 + ni*16 + lq*4) = o;
    }
  }
}

// ---------------- text projection: direct register GEMM, no LDS, no barriers ----
// T[g][n] = text[gperm[g]][:] @ W2fold[n][:]. Tile M=64 x N=256 per block.
// Per lane (swapped mfma, k_gru-verified formulas): frag (mi,ni) output
// row = m0+mi*16+l15, cols c0+ni*16+lq*4+{0..3}.
//   a[mi] = fp32->bf16 of text[gperm[row]][ks*32+lq*8 ..+8]  (2x float4)
//   b[ni] = WbT[(c0+ni*16+l15)*768 + 256 + ks*32+lq*8 ..+8]  (L2-hot)
// Latency hidden by TLP (no barriers) + compiler pipelining over unrolled ks.
__global__ __launch_bounds__(256,4) void k_projt(
    const float* __restrict__ text, const int* __restrict__ gperm,
    const bf16* __restrict__ WbT, bf16* __restrict__ out)
{
  int m0 = blockIdx.x*64;
  int tid = threadIdx.x, lane = tid&63, w = tid>>6;
  int l15 = lane&15, lq = lane>>4;
  int c0 = w*64;

  const float* ap[4];
  #pragma unroll
  for (int mi=0;mi<4;++mi)
    ap[mi] = text + (size_t)gperm[m0 + mi*16 + l15]*256 + lq*8;
  const bf16* bp = WbT + (size_t)(c0 + l15)*768 + 256 + lq*8;

  f32x4 acc[4][4];
  f32x4 z4 = {0.f,0.f,0.f,0.f};
  #pragma unroll
  for (int mi=0;mi<4;++mi)
    #pragma unroll
    for (int ni=0;ni<4;++ni) acc[mi][ni]=z4;

  #pragma unroll
  for (int ks=0; ks<8; ++ks){
    bf16x8 a[4], b[4];
    #pragma unroll
    for (int mi=0;mi<4;++mi){
      const float* sp = ap[mi] + ks*32;
      float4 u = ((const float4*)sp)[0], v = ((const float4*)sp)[1];
      bf16x8 o;
      o[0]=(bf16)u.x; o[1]=(bf16)u.y; o[2]=(bf16)u.z; o[3]=(bf16)u.w;
      o[4]=(bf16)v.x; o[5]=(bf16)v.y; o[6]=(bf16)v.z; o[7]=(bf16)v.w;
      a[mi] = o;
    }
    #pragma unroll
    for (int ni=0;ni<4;++ni)
      b[ni] = *(const bf16x8*)(bp + (size_t)ni*16*768 + ks*32);
    #pragma unroll
    for (int mi=0;mi<4;++mi)
      #pragma unroll
      for (int ni=0;ni<4;++ni)
        acc[mi][ni] = __builtin_amdgcn_mfma_f32_16x16x32_bf16(b[ni], a[mi], acc[mi][ni], 0,0,0);
  }

  #pragma unroll
  for (int mi=0;mi<4;++mi){
    int row = m0 + mi*16 + l15;
    #pragma unroll
    for (int ni=0;ni<4;++ni){
      bf16x4 o;
      #pragma unroll
      for (int q=0;q<4;++q) o[q] = (bf16)acc[mi][ni][q];
      *(bf16x4*)(out + (size_t)row*256 + c0 + ni*16 + lq*4) = o;
    }
  }
}

// ---------------- combine: gather P/Q/T + bias + relu + segment mean ----------------
__global__ __launch_bounds__(256) void k_comb(
    const bf16* __restrict__ P, const bf16* __restrict__ Q,
    const bf16* __restrict__ T, const float* __restrict__ bfused,
    const int* __restrict__ src_p, const int* __restrict__ dst_p,
    const int* __restrict__ counts, const int* __restrict__ offs,
    bf16* __restrict__ rel_bf)
{
  int r = blockIdx.x, t = blockIdx.y;
  int tid = threadIdx.x;
  int tr = t*256 + r;
  int nE = counts[tr];
  if (nE == 0){
    rel_bf[(size_t)tr*256 + tid] = (bf16)0.f;
    return;
  }
  int base = offs[tr];
  int es = tid>>5, cg = (tid&31)*8;
  float bb[8];
  {
    float4 b0 = *(const float4*)(bfused + cg);
    float4 b1 = *(const float4*)(bfused + cg + 4);
    bb[0]=b0.x; bb[1]=b0.y; bb[2]=b0.z; bb[3]=b0.w;
    bb[4]=b1.x; bb[5]=b1.y; bb[6]=b1.z; bb[7]=b1.w;
  }
  float acc[8];
  #pragma unroll
  for (int j=0;j<8;++j) acc[j]=0.f;
  for (int i = es; i < nE; i += 8){
    size_t g = (size_t)t*EE + base + i;
    int s = src_p[g], d = dst_p[g];
    bf16x8 pv = *(const bf16x8*)(P + (size_t)s*256 + cg);
    bf16x8 qv = *(const bf16x8*)(Q + (size_t)d*256 + cg);
    bf16x8 tv = *(const bf16x8*)(T + g*256 + cg);
    #pragma unroll
    for (int j=0;j<8;++j)
      acc[j] += fmaxf((float)pv[j] + (float)qv[j] + (float)tv[j] + bb[j], 0.f);
  }
  __shared__ float red[8][256];
  #pragma unroll
  for (int j=0;j<8;++j) red[es][cg+j] = acc[j];
  __syncthreads();
  float s = 0.f;
  #pragma unroll
  for (int e=0;e<8;++e) s += red[e][tid];
  rel_bf[(size_t)tr*256 + tid] = (bf16)(s / (float)nE);
}

// ---------------- plain bf16 GEMM (GI), K=256, out f32 stride 768 ----------------
__global__ __launch_bounds__(256) void k_gemm(
    const bf16* __restrict__ A, const bf16* __restrict__ BT,
    const float* __restrict__ bias, float* __restrict__ Out)
{
  int m0 = blockIdx.x*128, n0 = blockIdx.y*128;
  int tid = threadIdx.x, lane = tid&63, w = tid>>6;
  int l15 = lane&15, lq = lane>>4;
  __shared__ __align__(16) bf16 Al[128*32];
  __shared__ __align__(16) bf16 Bl[128*32];
  int wr = (w&1)*64, wc = (w>>1)*64;
  f32x4 acc[4][4];
  f32x4 z4 = {0.f,0.f,0.f,0.f};
  #pragma unroll
  for (int mi=0;mi<4;++mi)
    #pragma unroll
    for (int ni=0;ni<4;++ni) acc[mi][ni]=z4;
  for (int ks=0; ks<8; ++ks){
    int k0 = ks*32;
    #pragma unroll
    for (int p=0;p<2;++p){
      int c = p*256 + tid;
      int rw = c>>2, part = c&3;
      int pp = part ^ ((rw>>1)&3);
      const char* src = (const char*)(A + (size_t)(m0+rw)*256 + k0) + pp*16;
      gload16(src, (char*)Al + (size_t)(p*256 + w*64)*16);
    }
    #pragma unroll
    for (int p=0;p<2;++p){
      int c = p*256 + tid;
      int nn = c>>2, part = c&3;
      int pp = part ^ ((nn>>1)&3);
      const char* src = (const char*)(BT + (size_t)(n0+nn)*256 + k0) + pp*16;
      gload16(src, (char*)Bl + (size_t)(p*256 + w*64)*16);
    }
    __syncthreads();
    bf16x8 a[4], b[4];
    #pragma unroll
    for (int mi=0;mi<4;++mi){
      int rw = wr + mi*16 + l15;
      a[mi] = *(const bf16x8*)((const char*)Al + (size_t)rw*64 + (size_t)((lq ^ ((rw>>1)&3))*16));
    }
    #pragma unroll
    for (int ni=0;ni<4;++ni){
      int nn = wc + ni*16 + l15;
      b[ni] = *(const bf16x8*)((const char*)Bl + (size_t)nn*64 + (size_t)((lq ^ ((nn>>1)&3))*16));
    }
    #pragma unroll
    for (int mi=0;mi<4;++mi)
      #pragma unroll
      for (int ni=0;ni<4;++ni)
        acc[mi][ni] = __builtin_amdgcn_mfma_f32_16x16x32_bf16(a[mi], b[ni], acc[mi][ni], 0,0,0);
    __syncthreads();
  }
  #pragma unroll
  for (int ni=0;ni<4;++ni){
    int col = n0 + wc + ni*16 + l15;
    float bv = bias[col];
    #pragma unroll
    for (int mi=0;mi<4;++mi){
      #pragma unroll
      for (int q=0;q<4;++q){
        int row = m0 + wr + mi*16 + lq*4 + q;
        Out[(size_t)row*768 + col] = acc[mi][ni][q] + bv;
      }
    }
  }
}

// ---------------- fused whole-sequence GRU ----------------
__global__ __launch_bounds__(256) void k_gru(
    const float* __restrict__ GI, const bf16* __restrict__ WhhT,
    const float* __restrict__ bhh, const int* __restrict__ time_idx,
    float* __restrict__ out)
{
  int blk = blockIdx.x;           // 16 rows: blk*16 .. blk*16+15
  int tid = threadIdx.x, lane = tid&63, w = tid>>6;
  int l15 = lane&15, lq = lane>>4;
  int b = blk >> 4;               // batch index (256 rows per b)
  int rr = ((blk & 15)*16) + l15; // rel index of this lane's row
  __shared__ __align__(16) bf16 Ah[16*256];   // 8KB h rows (bf16)

  f32x4 h[4];
  #pragma unroll
  for (int jq=0;jq<4;++jq) h[jq] = f32x4{0.f,0.f,0.f,0.f};

  for (int s=0; s<SEQQ; ++s){
    int t = time_idx[b*SEQQ + s];
    size_t gib = (size_t)(t*256 + rr)*768;
    f32x4 gh[12];
    #pragma unroll
    for (int ni=0;ni<12;++ni){
      int col = (ni>>2)*256 + w*64 + (ni&3)*16 + lq*4;
      gh[ni] = *(const f32x4*)(bhh + col);
    }
    if (s > 0){
      #pragma unroll
      for (int ks=0; ks<8; ++ks){
        bf16x8 a = *(const bf16x8*)(&Ah[0] + (size_t)l15*256 + ks*32 + lq*8);
        #pragma unroll
        for (int ni=0;ni<12;++ni){
          int n = (ni>>2)*256 + w*64 + (ni&3)*16 + l15;
          bf16x8 wv = *(const bf16x8*)(WhhT + (size_t)n*256 + ks*32 + lq*8);
          gh[ni] = __builtin_amdgcn_mfma_f32_16x16x32_bf16(wv, a, gh[ni], 0,0,0);
        }
      }
    }
    #pragma unroll
    for (int jq=0;jq<4;++jq){
      int col = w*64 + jq*16 + lq*4;
      f32x4 ir = *(const f32x4*)(GI + gib + col);
      f32x4 iz = *(const f32x4*)(GI + gib + 256 + col);
      f32x4 in = *(const f32x4*)(GI + gib + 512 + col);
      #pragma unroll
      for (int q=0;q<4;++q){
        float rg = 1.f/(1.f + __expf(-(ir[q] + gh[jq][q])));
        float zz = 1.f/(1.f + __expf(-(iz[q] + gh[4+jq][q])));
        float nn = tanhf(in[q] + rg*gh[8+jq][q]);
        h[jq][q] = (1.f - zz)*nn + zz*h[jq][q];
      }
    }
    if (s < SEQQ-1){
      __syncthreads();
      #pragma unroll
      for (int jq=0;jq<4;++jq){
        bf16x4 o;
        #pragma unroll
        for (int q=0;q<4;++q) o[q] = (bf16)h[jq][q];
        *(bf16x4*)(&Ah[0] + (size_t)l15*256 + w*64 + jq*16 + lq*4) = o;
      }
      __syncthreads();
    }
  }
  #pragma unroll
  for (int jq=0;jq<4;++jq){
    f32x4 o = h[jq];
    *(f32x4*)(out + (size_t)(blk*16 + l15)*256 + w*64 + jq*16 + lq*4) = o;
  }
}

// ---------------- launch ----------------
extern "C" void kernel_launch(void* const* d_in, const int* in_sizes, int n_in,
                              void* d_out, int out_size, void* d_ws, size_t ws_size,
                              hipStream_t stream)
{
  (void)in_sizes; (void)n_in; (void)out_size; (void)ws_size;
  const float* node_embeds = (const float*)d_in[0];
  const float* text_emb    = (const float*)d_in[1];
  const float* text_w_W    = (const float*)d_in[2];
  const float* text_w_b    = (const float*)d_in[3];
  const float* edge_w_W    = (const float*)d_in[4];
  const float* edge_w_b    = (const float*)d_in[5];
  const float* gru_Wih     = (const float*)d_in[6];
  const float* gru_Whh     = (const float*)d_in[7];
  const float* gru_bih     = (const float*)d_in[8];
  const float* gru_bhh     = (const float*)d_in[9];
  const int* edge_src      = (const int*)d_in[10];
  const int* edge_dst      = (const int*)d_in[11];
  const int* edge_rel      = (const int*)d_in[12];
  const int* time_idx      = (const int*)d_in[13];
  float* out = (float*)d_out;
  char* ws = (char*)d_ws;

  size_t o = 0;
  bf16*  WbT    = (bf16*) (ws + o); o += (size_t)768*256*2;
  bf16*  WihT   = (bf16*) (ws + o); o += (size_t)768*256*2;
  bf16*  WhhT   = (bf16*) (ws + o); o += (size_t)768*256*2;
  float* bfused = (float*)(ws + o); o += 1024;
  bf16*  node_bf= (bf16*) (ws + o); o += (size_t)NPAD*256*2;      // 25.6MB
  int*   counts = (int*)  (ws + o); o += (size_t)TT*256*4;
  int*   offs   = (int*)  (ws + o); o += (size_t)TT*256*4;
  int*   cursor = (int*)  (ws + o); o += (size_t)TT*256*4;
  int*   gperm  = (int*)  (ws + o); o += (size_t)TT*EE*4;
  int*   src_p  = (int*)  (ws + o); o += (size_t)TT*EE*4;
  int*   dst_p  = (int*)  (ws + o); o += (size_t)TT*EE*4;
  bf16*  rel_bf = (bf16*) (ws + o); o += (size_t)TT*256*256*2;
  bf16*  P      = (bf16*) (ws + o); o += (size_t)NPAD*256*2;      // 25.6MB
  bf16*  Q      = (bf16*) (ws + o); o += (size_t)NPAD*256*2;      // 25.6MB
  // Tproj (245.8MB) aliases GI region: Tproj's last read (k_comb) precedes
  // the first GI write (k_gemm) in stream order.
  size_t oT = o;
  bf16*  Tproj  = (bf16*) (ws + oT);
  float* GI     = (float*)(ws + oT);   // 18.9MB (within Tproj footprint)

  k_cvt8<<<6250,256,0,stream>>>(node_embeds, node_bf, NNODES*256/8);
  k_build_wbt<<<256,256,0,stream>>>(text_w_W, edge_w_W, WbT);
  k_bias<<<1,256,0,stream>>>(text_w_b, edge_w_W, edge_w_b, bfused);
  k_gruWT<<<768,256,0,stream>>>(gru_Wih, WihT);
  k_gruWT<<<768,256,0,stream>>>(gru_Whh, WhhT);
  k_hist<<<TT,256,0,stream>>>(edge_rel, counts, offs, cursor);
  k_perm<<<dim3((EE+255)/256,TT),256,0,stream>>>(edge_rel, edge_src, edge_dst,
                                                 cursor, gperm, src_p, dst_p);
  k_projn<<<NPAD/128,256,0,stream>>>(node_bf, WbT, 0,   P);
  k_projn<<<NPAD/128,256,0,stream>>>(node_bf, WbT, 512, Q);
  k_projt<<<TT*EE/64,256,0,stream>>>(text_emb, gperm, WbT, Tproj);
  k_comb<<<dim3(256,TT),256,0,stream>>>(P, Q, Tproj, bfused, src_p, dst_p,
                                        counts, offs, rel_bf);
  // GI = rel_emb @ Wih + bih  (M=6144)
  k_gemm<<<dim3(48,6),256,0,stream>>>(rel_bf, WihT, gru_bih, GI);
  // whole GRU sequence in one kernel
  k_gru<<<256,256,0,stream>>>(GI, WhhT, gru_bhh, time_idx, out);
}

// Round 10
// 566.238 us; speedup vs baseline: 1.3293x; 1.3293x over previous
//
#include <hip/hip_runtime.h>
#include <cstdint>
#include <cstddef>

#define NNODES 50000
#define NPAD   50048        // 391*128, padded M for P/Q GEMM
#define NRELS  256
#define DIM    256
#define TT     24
#define EE     20000
#define BATCH  16
#define SEQQ   7

typedef __bf16 bf16;
typedef __bf16 bf16x4 __attribute__((ext_vector_type(4)));
typedef __bf16 bf16x8 __attribute__((ext_vector_type(8)));
typedef float  f32x4  __attribute__((ext_vector_type(4)));

// async global->LDS, 16B per lane; dest is wave-uniform base (+lane*16 by HW)
__device__ __forceinline__ void gload16(const void* g, void* l){
  __builtin_amdgcn_global_load_lds((const __attribute__((address_space(1))) void*)g,
                                   (__attribute__((address_space(3))) void*)l, 16, 0, 0);
}

// ---------------- prep kernels ----------------

__global__ void k_cvt8(const float* __restrict__ in, bf16* __restrict__ out, int n8){
  int i = blockIdx.x*256 + threadIdx.x;
  if (i >= n8) return;
  const float4* p = (const float4*)in + (size_t)i*2;
  float4 a = p[0], b = p[1];
  bf16x8 o;
  o[0]=(bf16)a.x; o[1]=(bf16)a.y; o[2]=(bf16)a.z; o[3]=(bf16)a.w;
  o[4]=(bf16)b.x; o[5]=(bf16)b.y; o[6]=(bf16)b.z; o[7]=(bf16)b.w;
  ((bf16x8*)out)[i] = o;
}

// Fused edge weight, transposed: WbT[n][k], k in [0,768) = [W1 | W2fold | W3].
__global__ void k_build_wbt(const float* __restrict__ tW, const float* __restrict__ eW,
                            bf16* __restrict__ WbT){
  int n = blockIdx.x, j = threadIdx.x;
  WbT[(size_t)n*768 + j]       = (bf16)eW[(size_t)j*256 + n];
  WbT[(size_t)n*768 + 512 + j] = (bf16)eW[(size_t)(512+j)*256 + n];
  float acc = 0.f;
  for (int m=0; m<256; ++m) acc += tW[(size_t)j*256 + m] * eW[(size_t)(256+m)*256 + n];
  WbT[(size_t)n*768 + 256 + j] = (bf16)acc;
}

// fused bias: bfused[n] = edge_w_b[n] + sum_m text_w_b[m]*W2[m][n]
__global__ void k_bias(const float* __restrict__ tb, const float* __restrict__ eW,
                       const float* __restrict__ eb, float* __restrict__ bf){
  int n = threadIdx.x;
  float acc = eb[n];
  for (int m=0; m<256; ++m) acc += tb[m] * eW[(size_t)(256+m)*256 + n];
  bf[n] = acc;
}

// gru weight [256][768] -> transposed bf16 [768][256]
__global__ void k_gruWT(const float* __restrict__ W, bf16* __restrict__ WT){
  int n = blockIdx.x, k = threadIdx.x;
  WT[(size_t)n*256 + k] = (bf16)W[(size_t)k*768 + n];
}

// per-t histogram of rels + exclusive scan
__global__ void k_hist(const int* __restrict__ rel, int* __restrict__ counts,
                       int* __restrict__ offs, int* __restrict__ cursor){
  __shared__ int hist[256];
  __shared__ int scan[256];
  int t = blockIdx.x, tid = threadIdx.x;
  hist[tid] = 0;
  __syncthreads();
  for (int e = tid; e < EE; e += 256) atomicAdd(&hist[rel[(size_t)t*EE + e]], 1);
  __syncthreads();
  int v = hist[tid];
  scan[tid] = v;
  __syncthreads();
  for (int d=1; d<256; d<<=1){
    int add = (tid >= d) ? scan[tid-d] : 0;
    __syncthreads();
    scan[tid] += add;
    __syncthreads();
  }
  int ex = scan[tid] - v;
  counts[t*256+tid] = v;
  offs[t*256+tid]   = ex;
  cursor[t*256+tid] = ex;
}

// bucket edges by (t,rel): emit global text row index and src/dst ids
__global__ void k_perm(const int* __restrict__ rel, const int* __restrict__ esrc,
                       const int* __restrict__ edst, int* __restrict__ cursor,
                       int* __restrict__ gperm, int* __restrict__ src_p,
                       int* __restrict__ dst_p){
  int t = blockIdx.y;
  int e = blockIdx.x*256 + threadIdx.x;
  if (e < EE){
    int r = rel[(size_t)t*EE + e];
    int p = atomicAdd(&cursor[t*256 + r], 1);
    size_t g = (size_t)t*EE + p;
    gperm[g] = t*EE + e;
    src_p[g] = esrc[(size_t)t*EE + e];
    dst_p[g] = edst[(size_t)t*EE + e];
  }
}

// ---------------- node projection GEMM (swapped operands, coalesced stores) ----
__global__ __launch_bounds__(256) void k_projn(
    const bf16* __restrict__ Abf, const bf16* __restrict__ WbT, int koff,
    bf16* __restrict__ out)
{
  int m0 = blockIdx.x*128;
  int tid = threadIdx.x, lane = tid&63, w = tid>>6;
  int l15 = lane&15, lq = lane>>4;
  int c0 = w*64;
  __shared__ __align__(16) bf16 Al[128*32];   // 8KB
  __shared__ __align__(16) bf16 Bl[256*32];   // 16KB

  f32x4 acc[8][4];
  f32x4 z4 = {0.f,0.f,0.f,0.f};
  #pragma unroll
  for (int mi=0;mi<8;++mi)
    #pragma unroll
    for (int ni=0;ni<4;++ni) acc[mi][ni]=z4;

  for (int ks=0; ks<8; ++ks){
    int k0 = ks*32;
    #pragma unroll
    for (int p=0;p<2;++p){
      int c = p*256 + tid;
      int rw = c>>2, prt = c&3;
      int pp = prt ^ ((rw>>1)&3);
      const char* src = (const char*)(Abf + (size_t)(m0+rw)*256 + k0) + pp*16;
      gload16(src, (char*)Al + (size_t)(p*256 + w*64)*16);
    }
    #pragma unroll
    for (int p=0;p<4;++p){
      int c = p*256 + tid;
      int nn = c>>2, prt = c&3;
      int pp = prt ^ ((nn>>1)&3);
      const char* src = (const char*)(WbT + (size_t)nn*768 + koff + k0) + pp*16;
      gload16(src, (char*)Bl + (size_t)(p*256 + w*64)*16);
    }
    __syncthreads();
    bf16x8 b[4];
    #pragma unroll
    for (int ni=0;ni<4;++ni){
      int nn = c0 + ni*16 + l15;
      b[ni] = *(const bf16x8*)((const char*)Bl + (size_t)nn*64 + (size_t)((lq ^ ((nn>>1)&3))*16));
    }
    #pragma unroll
    for (int mi=0;mi<8;++mi){
      int rw = mi*16 + l15;
      bf16x8 a = *(const bf16x8*)((const char*)Al + (size_t)rw*64 + (size_t)((lq ^ ((rw>>1)&3))*16));
      #pragma unroll
      for (int ni=0;ni<4;++ni)
        acc[mi][ni] = __builtin_amdgcn_mfma_f32_16x16x32_bf16(b[ni], a, acc[mi][ni], 0,0,0);
    }
    __syncthreads();
  }
  #pragma unroll
  for (int mi=0;mi<8;++mi){
    int row = m0 + mi*16 + l15;
    #pragma unroll
    for (int ni=0;ni<4;++ni){
      bf16x4 o;
      #pragma unroll
      for (int q=0;q<4;++q) o[q] = (bf16)acc[mi][ni][q];
      *(bf16x4*)(out + (size_t)row*256 + c0 + ni*16 + lq*4) = o;
    }
  }
}

// ---------------- text projection GEMM: double-buffered + counted vmcnt ----------
// T[g][n] = text[gperm[g]][:] @ W2fold[n][:]. Tile M=64 x N=256, 4 waves.
// Per step (T4/T14): issue A(ks+1)->regs (2 VMEM) + B(ks+1)->buf^1 (4 gload16),
// then vmcnt(6)+lgkmcnt(0)+s_barrier  -- drains only B(ks), keeps the 6 new
// loads in flight across the barrier. ds_read(bi) + lgkmcnt(0) + sched_barrier
// (rule 18), MFMA, cvt+ds_write A(ks+1) (compiler auto-waits vmcnt(4)), raw
// s_barrier. Writer's ds_write drains at the NEXT step's lgkmcnt(0) before the
// barrier its readers cross; buffers alternate so overwrite follows readers.
__global__ __launch_bounds__(256,4) void k_projt(
    const float* __restrict__ text, const int* __restrict__ gperm,
    const bf16* __restrict__ WbT, bf16* __restrict__ out)
{
  int m0 = blockIdx.x*64;
  int tid = threadIdx.x, lane = tid&63, w = tid>>6;
  int l15 = lane&15, lq = lane>>4;
  int c0 = w*64;
  __shared__ __align__(16) bf16 Al[2][64*32];    // 8KB
  __shared__ __align__(16) bf16 Bl[2][256*32];   // 32KB

  int r0 = tid>>2;
  int part = tid&3;
  int pp0 = part ^ ((r0>>1)&3);
  const float* aP0 = text + (size_t)gperm[m0 + r0]*256 + pp0*8;

#define LOADA(KS, U, V)                                            \
  { const float* sp_ = aP0 + (KS)*32;                              \
    U = ((const float4*)sp_)[0]; V = ((const float4*)sp_)[1]; }

#define WRITEA(BI, U, V)                                           \
  { bf16x8 o_;                                                     \
    o_[0]=(bf16)U.x; o_[1]=(bf16)U.y; o_[2]=(bf16)U.z; o_[3]=(bf16)U.w; \
    o_[4]=(bf16)V.x; o_[5]=(bf16)V.y; o_[6]=(bf16)V.z; o_[7]=(bf16)V.w; \
    *(bf16x8*)((char*)&Al[BI][0] + (size_t)tid*16) = o_; }

#define STAGEB(KS, BI)                                             \
  { _Pragma("unroll")                                              \
    for (int p_=0;p_<4;++p_){                                      \
      int c_ = p_*256 + tid;                                       \
      int nn_ = c_>>2, prt_ = c_&3;                                \
      int pp_ = prt_ ^ ((nn_>>1)&3);                               \
      const char* src_ = (const char*)(WbT + (size_t)nn_*768 + 256 + (KS)*32) + pp_*16; \
      gload16(src_, (char*)&Bl[BI][0] + (size_t)(p_*256 + w*64)*16); } }

  f32x4 acc[4][4];
  f32x4 z4 = {0.f,0.f,0.f,0.f};
  #pragma unroll
  for (int mi=0;mi<4;++mi)
    #pragma unroll
    for (int ni=0;ni<4;++ni) acc[mi][ni]=z4;

  // prologue: stage step 0 into buf 0
  float4 u0, v0, u1, v1;
  LOADA(0, u0, v0);
  STAGEB(0, 0);
  WRITEA(0, u0, v0);      // compiler waits vmcnt(4) for u0/v0 (B(0) stays in flight)

  #pragma unroll
  for (int ks=0; ks<8; ++ks){
    const int bi = ks & 1;
    if (ks < 7){
      LOADA(ks+1, u1, v1);       // +2 VMEM
      STAGEB(ks+1, bi^1);        // +4 VMEM
      // drain B(ks) (oldest 4); keep the 6 just-issued in flight.
      // lgkmcnt(0): this wave's ds_write of A is complete before the barrier.
      asm volatile("s_waitcnt vmcnt(6) lgkmcnt(0)\n\ts_barrier" ::: "memory");
    } else {
      asm volatile("s_waitcnt vmcnt(0) lgkmcnt(0)\n\ts_barrier" ::: "memory");
    }
    __builtin_amdgcn_sched_barrier(0);
    bf16x8 a[4], b[4];
    #pragma unroll
    for (int ni=0;ni<4;++ni){
      int nn = c0 + ni*16 + l15;
      b[ni] = *(const bf16x8*)((const char*)&Bl[bi][0]
               + (size_t)nn*64 + (size_t)((lq ^ ((nn>>1)&3))*16));
    }
    #pragma unroll
    for (int mi=0;mi<4;++mi){
      int rw = mi*16 + l15;
      a[mi] = *(const bf16x8*)((const char*)&Al[bi][0]
               + (size_t)rw*64 + (size_t)((lq ^ ((rw>>1)&3))*16));
    }
    asm volatile("s_waitcnt lgkmcnt(0)" ::: "memory");
    __builtin_amdgcn_sched_barrier(0);
    #pragma unroll
    for (int mi=0;mi<4;++mi)
      #pragma unroll
      for (int ni=0;ni<4;++ni)
        acc[mi][ni] = __builtin_amdgcn_mfma_f32_16x16x32_bf16(b[ni], a[mi], acc[mi][ni], 0,0,0);
    if (ks < 7){
      WRITEA(bi^1, u1, v1);      // compiler auto-waits vmcnt(4) for u1/v1
      __builtin_amdgcn_s_barrier();   // readers of bi done (lgkm drained above)
    }
  }
#undef LOADA
#undef WRITEA
#undef STAGEB

  #pragma unroll
  for (int mi=0;mi<4;++mi){
    int row = m0 + mi*16 + l15;
    #pragma unroll
    for (int ni=0;ni<4;++ni){
      bf16x4 o;
      #pragma unroll
      for (int q=0;q<4;++q) o[q] = (bf16)acc[mi][ni][q];
      *(bf16x4*)(out + (size_t)row*256 + c0 + ni*16 + lq*4) = o;
    }
  }
}

// ---------------- combine: gather P/Q/T + bias + relu + segment mean ----------------
__global__ __launch_bounds__(256) void k_comb(
    const bf16* __restrict__ P, const bf16* __restrict__ Q,
    const bf16* __restrict__ T, const float* __restrict__ bfused,
    const int* __restrict__ src_p, const int* __restrict__ dst_p,
    const int* __restrict__ counts, const int* __restrict__ offs,
    bf16* __restrict__ rel_bf)
{
  int r = blockIdx.x, t = blockIdx.y;
  int tid = threadIdx.x;
  int tr = t*256 + r;
  int nE = counts[tr];
  if (nE == 0){
    rel_bf[(size_t)tr*256 + tid] = (bf16)0.f;
    return;
  }
  int base = offs[tr];
  int es = tid>>5, cg = (tid&31)*8;
  float bb[8];
  {
    float4 b0 = *(const float4*)(bfused + cg);
    float4 b1 = *(const float4*)(bfused + cg + 4);
    bb[0]=b0.x; bb[1]=b0.y; bb[2]=b0.z; bb[3]=b0.w;
    bb[4]=b1.x; bb[5]=b1.y; bb[6]=b1.z; bb[7]=b1.w;
  }
  float acc[8];
  #pragma unroll
  for (int j=0;j<8;++j) acc[j]=0.f;
  for (int i = es; i < nE; i += 8){
    size_t g = (size_t)t*EE + base + i;
    int s = src_p[g], d = dst_p[g];
    bf16x8 pv = *(const bf16x8*)(P + (size_t)s*256 + cg);
    bf16x8 qv = *(const bf16x8*)(Q + (size_t)d*256 + cg);
    bf16x8 tv = *(const bf16x8*)(T + g*256 + cg);
    #pragma unroll
    for (int j=0;j<8;++j)
      acc[j] += fmaxf((float)pv[j] + (float)qv[j] + (float)tv[j] + bb[j], 0.f);
  }
  __shared__ float red[8][256];
  #pragma unroll
  for (int j=0;j<8;++j) red[es][cg+j] = acc[j];
  __syncthreads();
  float s = 0.f;
  #pragma unroll
  for (int e=0;e<8;++e) s += red[e][tid];
  rel_bf[(size_t)tr*256 + tid] = (bf16)(s / (float)nE);
}

// ---------------- plain bf16 GEMM (GI), K=256, out f32 stride 768 ----------------
__global__ __launch_bounds__(256) void k_gemm(
    const bf16* __restrict__ A, const bf16* __restrict__ BT,
    const float* __restrict__ bias, float* __restrict__ Out)
{
  int m0 = blockIdx.x*128, n0 = blockIdx.y*128;
  int tid = threadIdx.x, lane = tid&63, w = tid>>6;
  int l15 = lane&15, lq = lane>>4;
  __shared__ __align__(16) bf16 Al[128*32];
  __shared__ __align__(16) bf16 Bl[128*32];
  int wr = (w&1)*64, wc = (w>>1)*64;
  f32x4 acc[4][4];
  f32x4 z4 = {0.f,0.f,0.f,0.f};
  #pragma unroll
  for (int mi=0;mi<4;++mi)
    #pragma unroll
    for (int ni=0;ni<4;++ni) acc[mi][ni]=z4;
  for (int ks=0; ks<8; ++ks){
    int k0 = ks*32;
    #pragma unroll
    for (int p=0;p<2;++p){
      int c = p*256 + tid;
      int rw = c>>2, part = c&3;
      int pp = part ^ ((rw>>1)&3);
      const char* src = (const char*)(A + (size_t)(m0+rw)*256 + k0) + pp*16;
      gload16(src, (char*)Al + (size_t)(p*256 + w*64)*16);
    }
    #pragma unroll
    for (int p=0;p<2;++p){
      int c = p*256 + tid;
      int nn = c>>2, part = c&3;
      int pp = part ^ ((nn>>1)&3);
      const char* src = (const char*)(BT + (size_t)(n0+nn)*256 + k0) + pp*16;
      gload16(src, (char*)Bl + (size_t)(p*256 + w*64)*16);
    }
    __syncthreads();
    bf16x8 a[4], b[4];
    #pragma unroll
    for (int mi=0;mi<4;++mi){
      int rw = wr + mi*16 + l15;
      a[mi] = *(const bf16x8*)((const char*)Al + (size_t)rw*64 + (size_t)((lq ^ ((rw>>1)&3))*16));
    }
    #pragma unroll
    for (int ni=0;ni<4;++ni){
      int nn = wc + ni*16 + l15;
      b[ni] = *(const bf16x8*)((const char*)Bl + (size_t)nn*64 + (size_t)((lq ^ ((nn>>1)&3))*16));
    }
    #pragma unroll
    for (int mi=0;mi<4;++mi)
      #pragma unroll
      for (int ni=0;ni<4;++ni)
        acc[mi][ni] = __builtin_amdgcn_mfma_f32_16x16x32_bf16(a[mi], b[ni], acc[mi][ni], 0,0,0);
    __syncthreads();
  }
  #pragma unroll
  for (int ni=0;ni<4;++ni){
    int col = n0 + wc + ni*16 + l15;
    float bv = bias[col];
    #pragma unroll
    for (int mi=0;mi<4;++mi){
      #pragma unroll
      for (int q=0;q<4;++q){
        int row = m0 + wr + mi*16 + lq*4 + q;
        Out[(size_t)row*768 + col] = acc[mi][ni][q] + bv;
      }
    }
  }
}

// ---------------- fused whole-sequence GRU ----------------
__global__ __launch_bounds__(256) void k_gru(
    const float* __restrict__ GI, const bf16* __restrict__ WhhT,
    const float* __restrict__ bhh, const int* __restrict__ time_idx,
    float* __restrict__ out)
{
  int blk = blockIdx.x;           // 16 rows: blk*16 .. blk*16+15
  int tid = threadIdx.x, lane = tid&63, w = tid>>6;
  int l15 = lane&15, lq = lane>>4;
  int b = blk >> 4;               // batch index (256 rows per b)
  int rr = ((blk & 15)*16) + l15; // rel index of this lane's row
  __shared__ __align__(16) bf16 Ah[16*256];   // 8KB h rows (bf16)

  f32x4 h[4];
  #pragma unroll
  for (int jq=0;jq<4;++jq) h[jq] = f32x4{0.f,0.f,0.f,0.f};

  for (int s=0; s<SEQQ; ++s){
    int t = time_idx[b*SEQQ + s];
    size_t gib = (size_t)(t*256 + rr)*768;
    f32x4 gh[12];
    #pragma unroll
    for (int ni=0;ni<12;++ni){
      int col = (ni>>2)*256 + w*64 + (ni&3)*16 + lq*4;
      gh[ni] = *(const f32x4*)(bhh + col);
    }
    if (s > 0){
      #pragma unroll
      for (int ks=0; ks<8; ++ks){
        bf16x8 a = *(const bf16x8*)(&Ah[0] + (size_t)l15*256 + ks*32 + lq*8);
        #pragma unroll
        for (int ni=0;ni<12;++ni){
          int n = (ni>>2)*256 + w*64 + (ni&3)*16 + l15;
          bf16x8 wv = *(const bf16x8*)(WhhT + (size_t)n*256 + ks*32 + lq*8);
          gh[ni] = __builtin_amdgcn_mfma_f32_16x16x32_bf16(wv, a, gh[ni], 0,0,0);
        }
      }
    }
    #pragma unroll
    for (int jq=0;jq<4;++jq){
      int col = w*64 + jq*16 + lq*4;
      f32x4 ir = *(const f32x4*)(GI + gib + col);
      f32x4 iz = *(const f32x4*)(GI + gib + 256 + col);
      f32x4 in = *(const f32x4*)(GI + gib + 512 + col);
      #pragma unroll
      for (int q=0;q<4;++q){
        float rg = 1.f/(1.f + __expf(-(ir[q] + gh[jq][q])));
        float zz = 1.f/(1.f + __expf(-(iz[q] + gh[4+jq][q])));
        float nn = tanhf(in[q] + rg*gh[8+jq][q]);
        h[jq][q] = (1.f - zz)*nn + zz*h[jq][q];
      }
    }
    if (s < SEQQ-1){
      __syncthreads();
      #pragma unroll
      for (int jq=0;jq<4;++jq){
        bf16x4 o;
        #pragma unroll
        for (int q=0;q<4;++q) o[q] = (bf16)h[jq][q];
        *(bf16x4*)(&Ah[0] + (size_t)l15*256 + w*64 + jq*16 + lq*4) = o;
      }
      __syncthreads();
    }
  }
  #pragma unroll
  for (int jq=0;jq<4;++jq){
    f32x4 o = h[jq];
    *(f32x4*)(out + (size_t)(blk*16 + l15)*256 + w*64 + jq*16 + lq*4) = o;
  }
}

// ---------------- launch ----------------
extern "C" void kernel_launch(void* const* d_in, const int* in_sizes, int n_in,
                              void* d_out, int out_size, void* d_ws, size_t ws_size,
                              hipStream_t stream)
{
  (void)in_sizes; (void)n_in; (void)out_size; (void)ws_size;
  const float* node_embeds = (const float*)d_in[0];
  const float* text_emb    = (const float*)d_in[1];
  const float* text_w_W    = (const float*)d_in[2];
  const float* text_w_b    = (const float*)d_in[3];
  const float* edge_w_W    = (const float*)d_in[4];
  const float* edge_w_b    = (const float*)d_in[5];
  const float* gru_Wih     = (const float*)d_in[6];
  const float* gru_Whh     = (const float*)d_in[7];
  const float* gru_bih     = (const float*)d_in[8];
  const float* gru_bhh     = (const float*)d_in[9];
  const int* edge_src      = (const int*)d_in[10];
  const int* edge_dst      = (const int*)d_in[11];
  const int* edge_rel      = (const int*)d_in[12];
  const int* time_idx      = (const int*)d_in[13];
  float* out = (float*)d_out;
  char* ws = (char*)d_ws;

  size_t o = 0;
  bf16*  WbT    = (bf16*) (ws + o); o += (size_t)768*256*2;
  bf16*  WihT   = (bf16*) (ws + o); o += (size_t)768*256*2;
  bf16*  WhhT   = (bf16*) (ws + o); o += (size_t)768*256*2;
  float* bfused = (float*)(ws + o); o += 1024;
  bf16*  node_bf= (bf16*) (ws + o); o += (size_t)NPAD*256*2;      // 25.6MB
  int*   counts = (int*)  (ws + o); o += (size_t)TT*256*4;
  int*   offs   = (int*)  (ws + o); o += (size_t)TT*256*4;
  int*   cursor = (int*)  (ws + o); o += (size_t)TT*256*4;
  int*   gperm  = (int*)  (ws + o); o += (size_t)TT*EE*4;
  int*   src_p  = (int*)  (ws + o); o += (size_t)TT*EE*4;
  int*   dst_p  = (int*)  (ws + o); o += (size_t)TT*EE*4;
  bf16*  rel_bf = (bf16*) (ws + o); o += (size_t)TT*256*256*2;
  bf16*  P      = (bf16*) (ws + o); o += (size_t)NPAD*256*2;      // 25.6MB
  bf16*  Q      = (bf16*) (ws + o); o += (size_t)NPAD*256*2;      // 25.6MB
  // Tproj (245.8MB) aliases GI region: Tproj's last read (k_comb) precedes
  // the first GI write (k_gemm) in stream order.
  size_t oT = o;
  bf16*  Tproj  = (bf16*) (ws + oT);
  float* GI     = (float*)(ws + oT);   // 18.9MB (within Tproj footprint)

  k_cvt8<<<6250,256,0,stream>>>(node_embeds, node_bf, NNODES*256/8);
  k_build_wbt<<<256,256,0,stream>>>(text_w_W, edge_w_W, WbT);
  k_bias<<<1,256,0,stream>>>(text_w_b, edge_w_W, edge_w_b, bfused);
  k_gruWT<<<768,256,0,stream>>>(gru_Wih, WihT);
  k_gruWT<<<768,256,0,stream>>>(gru_Whh, WhhT);
  k_hist<<<TT,256,0,stream>>>(edge_rel, counts, offs, cursor);
  k_perm<<<dim3((EE+255)/256,TT),256,0,stream>>>(edge_rel, edge_src, edge_dst,
                                                 cursor, gperm, src_p, dst_p);
  k_projn<<<NPAD/128,256,0,stream>>>(node_bf, WbT, 0,   P);
  k_projn<<<NPAD/128,256,0,stream>>>(node_bf, WbT, 512, Q);
  k_projt<<<TT*EE/64,256,0,stream>>>(text_emb, gperm, WbT, Tproj);
  k_comb<<<dim3(256,TT),256,0,stream>>>(P, Q, Tproj, bfused, src_p, dst_p,
                                        counts, offs, rel_bf);
  // GI = rel_emb @ Wih + bih  (M=6144)
  k_gemm<<<dim3(48,6),256,0,stream>>>(rel_bf, WihT, gru_bih, GI);
  // whole GRU sequence in one kernel
  k_gru<<<256,256,0,stream>>>(GI, WhhT, gru_bhh, time_idx, out);
}